// Round 3
// baseline (316.151 us; speedup 1.0000x reference)
//
#include <hip/hip_runtime.h>
#include <stdint.h>

typedef unsigned short u16;
typedef __attribute__((ext_vector_type(8))) short short8;
typedef __attribute__((ext_vector_type(4))) float f32x4;

__device__ __forceinline__ u16 f2bf(float f) {
    union { float f; uint32_t u; } v; v.f = f;
    uint32_t r = (v.u + 0x7fffu + ((v.u >> 16) & 1u)) >> 16;
    return (u16)r;
}

// ---------------------------------------------------------------------------
// x fp32 [4096*1024] -> bf16
// ---------------------------------------------------------------------------
__global__ void cvt_x(const float* __restrict__ x, u16* __restrict__ xb) {
    int i = (blockIdx.x * 256 + threadIdx.x) * 8;
    float4 a = *(const float4*)(x + i);
    float4 b = *(const float4*)(x + i + 4);
    union { u16 u[8]; uint4 v; } o;
    o.u[0] = f2bf(a.x); o.u[1] = f2bf(a.y); o.u[2] = f2bf(a.z); o.u[3] = f2bf(a.w);
    o.u[4] = f2bf(b.x); o.u[5] = f2bf(b.y); o.u[6] = f2bf(b.z); o.u[7] = f2bf(b.w);
    *(uint4*)(xb + i) = o.v;
}

// ---------------------------------------------------------------------------
// wq/wk/wv fp32 [K=1024][N=1024] -> wT bf16 [3][N][K]
// ---------------------------------------------------------------------------
__global__ void transpose3(const float* __restrict__ w0, const float* __restrict__ w1,
                           const float* __restrict__ w2, u16* __restrict__ out) {
    const int z = blockIdx.z;
    const float* in = (z == 0) ? w0 : (z == 1) ? w1 : w2;
    u16* o = out + (size_t)z * 1024 * 1024;
    __shared__ u16 tile[32][33];
    int x = blockIdx.x * 32 + threadIdx.x;
    int y0 = blockIdx.y * 32;
#pragma unroll
    for (int j = threadIdx.y; j < 32; j += 8)
        tile[j][threadIdx.x] = f2bf(in[(size_t)(y0 + j) * 1024 + x]);
    __syncthreads();
    int ox = blockIdx.y * 32 + threadIdx.x;
    int oy0 = blockIdx.x * 32;
#pragma unroll
    for (int j = threadIdx.y; j < 32; j += 8)
        o[(size_t)(oy0 + j) * 1024 + ox] = tile[threadIdx.x][j];
}

// ---------------------------------------------------------------------------
// GEMM (B^T bf16 input): C_bf16[M,N] = A_bf16[M,K] @ BT[N,K]^T + bias_f32.
// 128x128 tile, BK=32, 256 threads (4 waves 2x2), mfma_f32_16x16x32_bf16.
// ---------------------------------------------------------------------------
#define GBM 128
#define GBN 128
#define GBK 32
#define LDA 40

__global__ __launch_bounds__(256) void gemm_bt(
    const u16* __restrict__ A, int lda,
    const u16* __restrict__ BT, int ldb,
    const float* __restrict__ bias0, const float* __restrict__ bias1,
    const float* __restrict__ bias2,
    u16* __restrict__ C, int ldc, int K) {
    __shared__ __align__(16) u16 As[GBM * LDA];
    __shared__ __align__(16) u16 Bs[GBN * LDA];

    const int tid = threadIdx.x;
    const int wave = tid >> 6, lane = tid & 63;
    const int quad = lane >> 4, l16 = lane & 15;
    const int wr = wave >> 1, wc = wave & 1;
    const int m0 = blockIdx.y * GBM, n0 = blockIdx.x * GBN;

    const int seg = n0 >> 10;
    const float* bsel = (seg == 0) ? bias0 : (seg == 1) ? bias1 : bias2;

    f32x4 acc[4][4] = {};

    const int sr = tid >> 1;            // 0..127
    const int sc = (tid & 1) * 16;      // 0 or 16
    const u16* Ag = A + (size_t)(m0 + sr) * lda + sc;
    const u16* Bg = BT + (size_t)(n0 + sr) * ldb + sc;
    uint4* AsW = (uint4*)(As + sr * LDA + sc);
    uint4* BsW = (uint4*)(Bs + sr * LDA + sc);

    for (int kb = 0; kb < K; kb += GBK) {
        uint4 av0 = *(const uint4*)(Ag + kb);
        uint4 av1 = *(const uint4*)(Ag + kb + 8);
        uint4 bv0 = *(const uint4*)(Bg + kb);
        uint4 bv1 = *(const uint4*)(Bg + kb + 8);
        AsW[0] = av0; AsW[1] = av1;
        BsW[0] = bv0; BsW[1] = bv1;
        __syncthreads();

        short8 af[4], bf[4];
#pragma unroll
        for (int mt = 0; mt < 4; mt++)
            af[mt] = *(const short8*)(As + (wr * 64 + mt * 16 + l16) * LDA + quad * 8);
#pragma unroll
        for (int nt = 0; nt < 4; nt++)
            bf[nt] = *(const short8*)(Bs + (wc * 64 + nt * 16 + l16) * LDA + quad * 8);
#pragma unroll
        for (int mt = 0; mt < 4; mt++)
#pragma unroll
            for (int nt = 0; nt < 4; nt++)
                acc[mt][nt] = __builtin_amdgcn_mfma_f32_16x16x32_bf16(
                    af[mt], bf[nt], acc[mt][nt], 0, 0, 0);
        __syncthreads();
    }

#pragma unroll
    for (int nt = 0; nt < 4; nt++) {
        int col = n0 + wc * 64 + nt * 16 + l16;
        float bv = bsel[col & 1023];
#pragma unroll
        for (int mt = 0; mt < 4; mt++) {
            int row = m0 + wr * 64 + mt * 16 + quad * 4;
#pragma unroll
            for (int r = 0; r < 4; r++)
                C[(size_t)(row + r) * ldc + col] = f2bf(acc[mt][nt][r] + bv);
        }
    }
}

// ---------------------------------------------------------------------------
// GEMM (B fp32 natural [K][N], converted+transposed in LDS staging):
// C_f32 = A_bf16 @ bf16(B) + bias_f32.  Output projection.
// ---------------------------------------------------------------------------
__global__ __launch_bounds__(256) void gemm_kn(
    const u16* __restrict__ A, int lda,
    const float* __restrict__ B, int ldb,
    const float* __restrict__ bias,
    float* __restrict__ C, int ldc, int K) {
    __shared__ __align__(16) u16 As[GBM * LDA];
    __shared__ __align__(16) u16 Bs[GBN * LDA];

    const int tid = threadIdx.x;
    const int wave = tid >> 6, lane = tid & 63;
    const int quad = lane >> 4, l16 = lane & 15;
    const int wr = wave >> 1, wc = wave & 1;
    const int m0 = blockIdx.y * GBM, n0 = blockIdx.x * GBN;

    f32x4 acc[4][4] = {};

    const int sr = tid >> 1;            // 0..127
    const int sc = (tid & 1) * 16;      // 0 or 16
    const u16* Ag = A + (size_t)(m0 + sr) * lda + sc;
    uint4* AsW = (uint4*)(As + sr * LDA + sc);

    const int bk_ = tid >> 3;           // 0..31  (k within tile)
    const int bn_ = (tid & 7) * 16;     // 0..112 (n within tile)
    const float* Bg = B + (size_t)bk_ * ldb + n0 + bn_;

    for (int kb = 0; kb < K; kb += GBK) {
        uint4 av0 = *(const uint4*)(Ag + kb);
        uint4 av1 = *(const uint4*)(Ag + kb + 8);
        float4 b0 = *(const float4*)(Bg + (size_t)kb * ldb);
        float4 b1 = *(const float4*)(Bg + (size_t)kb * ldb + 4);
        float4 b2 = *(const float4*)(Bg + (size_t)kb * ldb + 8);
        float4 b3 = *(const float4*)(Bg + (size_t)kb * ldb + 12);
        u16 bu[16];
        bu[0]=f2bf(b0.x); bu[1]=f2bf(b0.y); bu[2]=f2bf(b0.z); bu[3]=f2bf(b0.w);
        bu[4]=f2bf(b1.x); bu[5]=f2bf(b1.y); bu[6]=f2bf(b1.z); bu[7]=f2bf(b1.w);
        bu[8]=f2bf(b2.x); bu[9]=f2bf(b2.y); bu[10]=f2bf(b2.z); bu[11]=f2bf(b2.w);
        bu[12]=f2bf(b3.x); bu[13]=f2bf(b3.y); bu[14]=f2bf(b3.z); bu[15]=f2bf(b3.w);
        AsW[0] = av0; AsW[1] = av1;
#pragma unroll
        for (int j = 0; j < 16; j++)
            Bs[(bn_ + j) * LDA + bk_] = bu[j];   // transpose: Bs[n][k]
        __syncthreads();

        short8 af[4], bf[4];
#pragma unroll
        for (int mt = 0; mt < 4; mt++)
            af[mt] = *(const short8*)(As + (wr * 64 + mt * 16 + l16) * LDA + quad * 8);
#pragma unroll
        for (int nt = 0; nt < 4; nt++)
            bf[nt] = *(const short8*)(Bs + (wc * 64 + nt * 16 + l16) * LDA + quad * 8);
#pragma unroll
        for (int mt = 0; mt < 4; mt++)
#pragma unroll
            for (int nt = 0; nt < 4; nt++)
                acc[mt][nt] = __builtin_amdgcn_mfma_f32_16x16x32_bf16(
                    af[mt], bf[nt], acc[mt][nt], 0, 0, 0);
        __syncthreads();
    }

#pragma unroll
    for (int nt = 0; nt < 4; nt++) {
        int col = n0 + wc * 64 + nt * 16 + l16;
        float bv = bias[col];
#pragma unroll
        for (int mt = 0; mt < 4; mt++) {
            int row = m0 + wr * 64 + mt * 16 + quad * 4;
#pragma unroll
            for (int r = 0; r < 4; r++)
                C[(size_t)(row + r) * ldc + col] = acc[mt][nt][r] + bv;
        }
    }
}

// ---------------------------------------------------------------------------
// Flash attention over QKV[4096][3072] bf16 (Q|K|V concat). Output written in
// place into the Q region (cols 0..1023): block (b,h,qt) loads its Q rows to
// registers first and is the only reader/writer of that (rows,cols) region.
// ---------------------------------------------------------------------------
#define SEQ 2048
#define BQ 64
#define BKV 64
#define LDK 72

__global__ __launch_bounds__(256) void attn(u16* __restrict__ QKV) {
    __shared__ __align__(16) u16 Ks[BKV * LDK];        // [kk][d]
    __shared__ __align__(16) u16 Vs[64 * LDK];         // [d][kk] (transposed)
    __shared__ __align__(16) u16 Ps[4 * 16 * LDK];     // per wave: [q][kk]

    const int tid = threadIdx.x;
    const int wave = tid >> 6, lane = tid & 63;
    const int quad = lane >> 4, l16 = lane & 15;
    const int h = blockIdx.y, bb = blockIdx.z;
    const int q0 = blockIdx.x * BQ;
    const size_t tok0 = (size_t)bb * SEQ;

    const u16* Qb = QKV + tok0 * 3072 + h * 64;
    const u16* Kb = QKV + tok0 * 3072 + 1024 + h * 64;
    const u16* Vb = QKV + tok0 * 3072 + 2048 + h * 64;

    const int qrow = q0 + wave * 16 + l16;
    short8 aq[2];
    aq[0] = *(const short8*)(Qb + (size_t)qrow * 3072 + quad * 8);
    aq[1] = *(const short8*)(Qb + (size_t)qrow * 3072 + 32 + quad * 8);

    float m_i[4], l_i[4];
#pragma unroll
    for (int r = 0; r < 4; r++) { m_i[r] = -1e30f; l_i[r] = 0.0f; }
    f32x4 o[4] = {};

    const int srow = tid >> 2;           // 0..63
    const int scc = (tid & 3) * 16;      // 0/16/32/48
    u16* Ps_w = Ps + wave * 16 * LDK;

    for (int j0 = 0; j0 < SEQ; j0 += BKV) {
        {
            const u16* kg = Kb + (size_t)(j0 + srow) * 3072 + scc;
            uint4 k0 = *(const uint4*)(kg);
            uint4 k1 = *(const uint4*)(kg + 8);
            *(uint4*)(Ks + srow * LDK + scc) = k0;
            *(uint4*)(Ks + srow * LDK + scc + 8) = k1;
            const u16* vg = Vb + (size_t)(j0 + srow) * 3072 + scc;
            union { uint4 v[2]; u16 u[16]; } vu;
            vu.v[0] = *(const uint4*)(vg);
            vu.v[1] = *(const uint4*)(vg + 8);
#pragma unroll
            for (int j = 0; j < 16; j++)
                Vs[(scc + j) * LDK + srow] = vu.u[j];
        }
        __syncthreads();

        f32x4 sacc[4];
#pragma unroll
        for (int kkt = 0; kkt < 4; kkt++) {
            f32x4 s = {};
#pragma unroll
            for (int k2 = 0; k2 < 2; k2++) {
                short8 bk = *(const short8*)(Ks + (kkt * 16 + l16) * LDK + k2 * 32 + quad * 8);
                s = __builtin_amdgcn_mfma_f32_16x16x32_bf16(aq[k2], bk, s, 0, 0, 0);
            }
            sacc[kkt] = s;
        }
#pragma unroll
        for (int kkt = 0; kkt < 4; kkt++)
#pragma unroll
            for (int r = 0; r < 4; r++) sacc[kkt][r] *= 0.125f;

        float rowmax[4];
#pragma unroll
        for (int r = 0; r < 4; r++) {
            float m = sacc[0][r];
            m = fmaxf(m, sacc[1][r]); m = fmaxf(m, sacc[2][r]); m = fmaxf(m, sacc[3][r]);
            rowmax[r] = m;
        }
#pragma unroll
        for (int off = 1; off < 16; off <<= 1)
#pragma unroll
            for (int r = 0; r < 4; r++)
                rowmax[r] = fmaxf(rowmax[r], __shfl_xor(rowmax[r], off, 64));

        float alpha[4];
#pragma unroll
        for (int r = 0; r < 4; r++) {
            float mn = fmaxf(m_i[r], rowmax[r]);
            alpha[r] = __expf(m_i[r] - mn);
            m_i[r] = mn;
        }
#pragma unroll
        for (int kkt = 0; kkt < 4; kkt++)
#pragma unroll
            for (int r = 0; r < 4; r++)
                sacc[kkt][r] = __expf(sacc[kkt][r] - m_i[r]);

        float lsum[4];
#pragma unroll
        for (int r = 0; r < 4; r++)
            lsum[r] = sacc[0][r] + sacc[1][r] + sacc[2][r] + sacc[3][r];
#pragma unroll
        for (int off = 1; off < 16; off <<= 1)
#pragma unroll
            for (int r = 0; r < 4; r++)
                lsum[r] += __shfl_xor(lsum[r], off, 64);
#pragma unroll
        for (int r = 0; r < 4; r++)
            l_i[r] = l_i[r] * alpha[r] + lsum[r];

#pragma unroll
        for (int dt = 0; dt < 4; dt++)
#pragma unroll
            for (int r = 0; r < 4; r++) o[dt][r] *= alpha[r];

#pragma unroll
        for (int kkt = 0; kkt < 4; kkt++)
#pragma unroll
            for (int r = 0; r < 4; r++)
                Ps_w[(quad * 4 + r) * LDK + kkt * 16 + l16] = f2bf(sacc[kkt][r]);
        __syncthreads();

        short8 ap[2];
        ap[0] = *(const short8*)(Ps_w + l16 * LDK + quad * 8);
        ap[1] = *(const short8*)(Ps_w + l16 * LDK + 32 + quad * 8);
#pragma unroll
        for (int dt = 0; dt < 4; dt++) {
            f32x4 c = o[dt];
#pragma unroll
            for (int k2 = 0; k2 < 2; k2++) {
                short8 bv = *(const short8*)(Vs + (dt * 16 + l16) * LDK + k2 * 32 + quad * 8);
                c = __builtin_amdgcn_mfma_f32_16x16x32_bf16(ap[k2], bv, c, 0, 0, 0);
            }
            o[dt] = c;
        }
        __syncthreads();
    }

    float inv_l[4];
#pragma unroll
    for (int r = 0; r < 4; r++) inv_l[r] = 1.0f / l_i[r];
#pragma unroll
    for (int dt = 0; dt < 4; dt++)
#pragma unroll
        for (int r = 0; r < 4; r++) {
            size_t row = tok0 + q0 + wave * 16 + quad * 4 + r;
            QKV[row * 3072 + h * 64 + dt * 16 + l16] = f2bf(o[dt][r] * inv_l[r]);
        }
}

// ---------------------------------------------------------------------------
extern "C" void kernel_launch(void* const* d_in, const int* in_sizes, int n_in,
                              void* d_out, int out_size, void* d_ws, size_t ws_size,
                              hipStream_t stream) {
    const float* x  = (const float*)d_in[0];
    const float* wq = (const float*)d_in[1];
    const float* bq = (const float*)d_in[2];
    const float* wk = (const float*)d_in[3];
    const float* bk = (const float*)d_in[4];
    const float* wv = (const float*)d_in[5];
    const float* bv = (const float*)d_in[6];
    const float* wo = (const float*)d_in[7];
    const float* bo = (const float*)d_in[8];
    (void)in_sizes; (void)n_in; (void)out_size; (void)ws_size;

    u16* QKV = (u16*)d_ws;                              // [4096][3072] bf16, 24 MB
    u16* wT  = QKV + (size_t)4096 * 3072;               // [3][1024][1024] bf16, 6 MB
    u16* xb  = wT + (size_t)3 * 1024 * 1024;            // [4096][1024] bf16, 8 MB
    // total ws use: 38 MB

    cvt_x<<<dim3(2048), dim3(256), 0, stream>>>(x, xb);
    transpose3<<<dim3(32, 32, 3), dim3(32, 8), 0, stream>>>(wq, wk, wv, wT);
    gemm_bt<<<dim3(24, 32), 256, 0, stream>>>(xb, 1024, wT, 1024, bq, bk, bv,
                                              QKV, 3072, 1024);
    attn<<<dim3(32, 16, 2), 256, 0, stream>>>(QKV);
    gemm_kn<<<dim3(8, 32), 256, 0, stream>>>(QKV, 3072, wo, 1024, bo,
                                             (float*)d_out, 1024, 1024);
}

// Round 4
// 273.394 us; speedup vs baseline: 1.1564x; 1.1564x over previous
//
#include <hip/hip_runtime.h>
#include <stdint.h>

typedef unsigned short u16;
typedef __attribute__((ext_vector_type(8))) short short8;
typedef __attribute__((ext_vector_type(4))) float f32x4;

__device__ __forceinline__ u16 f2bf(float f) {
    union { float f; uint32_t u; } v; v.f = f;
    uint32_t r = (v.u + 0x7fffu + ((v.u >> 16) & 1u)) >> 16;
    return (u16)r;
}
__device__ __forceinline__ void store_out(u16* p, float v) { *p = f2bf(v); }
__device__ __forceinline__ void store_out(float* p, float v) { *p = v; }

// ---------------------------------------------------------------------------
// x fp32 [4096*1024] -> bf16
// ---------------------------------------------------------------------------
__global__ void cvt_x(const float* __restrict__ x, u16* __restrict__ xb) {
    int i = (blockIdx.x * 256 + threadIdx.x) * 8;
    float4 a = *(const float4*)(x + i);
    float4 b = *(const float4*)(x + i + 4);
    union { u16 u[8]; uint4 v; } o;
    o.u[0] = f2bf(a.x); o.u[1] = f2bf(a.y); o.u[2] = f2bf(a.z); o.u[3] = f2bf(a.w);
    o.u[4] = f2bf(b.x); o.u[5] = f2bf(b.y); o.u[6] = f2bf(b.z); o.u[7] = f2bf(b.w);
    *(uint4*)(xb + i) = o.v;
}

// ---------------------------------------------------------------------------
// fp32 [1024][1024] -> bf16 transposed; z selects among 3 sources
// ---------------------------------------------------------------------------
__global__ void transpose3(const float* __restrict__ w0, const float* __restrict__ w1,
                           const float* __restrict__ w2, u16* __restrict__ out) {
    const int z = blockIdx.z;
    const float* in = (z == 0) ? w0 : (z == 1) ? w1 : w2;
    u16* o = out + (size_t)z * 1024 * 1024;
    __shared__ u16 tile[32][33];
    int x = blockIdx.x * 32 + threadIdx.x;
    int y0 = blockIdx.y * 32;
#pragma unroll
    for (int j = threadIdx.y; j < 32; j += 8)
        tile[j][threadIdx.x] = f2bf(in[(size_t)(y0 + j) * 1024 + x]);
    __syncthreads();
    int ox = blockIdx.y * 32 + threadIdx.x;
    int oy0 = blockIdx.x * 32;
#pragma unroll
    for (int j = threadIdx.y; j < 32; j += 8)
        o[(size_t)(oy0 + j) * 1024 + ox] = tile[threadIdx.x][j];
}

// ---------------------------------------------------------------------------
// GEMM (B^T bf16): C[M,N] = A_bf16[M,K] @ BT[N,K]^T + bias_f32. OutT=u16/float.
// 128x128 tile, BK=32, 256 threads (4 waves 2x2), mfma_f32_16x16x32_bf16.
// ---------------------------------------------------------------------------
#define GBM 128
#define GBN 128
#define GBK 32
#define LDA 40

template <typename OutT>
__global__ __launch_bounds__(256) void gemm_bt(
    const u16* __restrict__ A, int lda,
    const u16* __restrict__ BT, int ldb,
    const float* __restrict__ bias0, const float* __restrict__ bias1,
    const float* __restrict__ bias2,
    OutT* __restrict__ C, int ldc, int K) {
    __shared__ __align__(16) u16 As[GBM * LDA];
    __shared__ __align__(16) u16 Bs[GBN * LDA];

    const int tid = threadIdx.x;
    const int wave = tid >> 6, lane = tid & 63;
    const int quad = lane >> 4, l16 = lane & 15;
    const int wr = wave >> 1, wc = wave & 1;
    const int m0 = blockIdx.y * GBM, n0 = blockIdx.x * GBN;

    const int seg = n0 >> 10;
    const float* bsel = (seg == 0) ? bias0 : (seg == 1) ? bias1 : bias2;

    f32x4 acc[4][4] = {};

    const int sr = tid >> 1;            // 0..127
    const int sc = (tid & 1) * 16;      // 0 or 16
    const u16* Ag = A + (size_t)(m0 + sr) * lda + sc;
    const u16* Bg = BT + (size_t)(n0 + sr) * ldb + sc;
    uint4* AsW = (uint4*)(As + sr * LDA + sc);
    uint4* BsW = (uint4*)(Bs + sr * LDA + sc);

    for (int kb = 0; kb < K; kb += GBK) {
        uint4 av0 = *(const uint4*)(Ag + kb);
        uint4 av1 = *(const uint4*)(Ag + kb + 8);
        uint4 bv0 = *(const uint4*)(Bg + kb);
        uint4 bv1 = *(const uint4*)(Bg + kb + 8);
        AsW[0] = av0; AsW[1] = av1;
        BsW[0] = bv0; BsW[1] = bv1;
        __syncthreads();

        short8 af[4], bf[4];
#pragma unroll
        for (int mt = 0; mt < 4; mt++)
            af[mt] = *(const short8*)(As + (wr * 64 + mt * 16 + l16) * LDA + quad * 8);
#pragma unroll
        for (int nt = 0; nt < 4; nt++)
            bf[nt] = *(const short8*)(Bs + (wc * 64 + nt * 16 + l16) * LDA + quad * 8);
#pragma unroll
        for (int mt = 0; mt < 4; mt++)
#pragma unroll
            for (int nt = 0; nt < 4; nt++)
                acc[mt][nt] = __builtin_amdgcn_mfma_f32_16x16x32_bf16(
                    af[mt], bf[nt], acc[mt][nt], 0, 0, 0);
        __syncthreads();
    }

#pragma unroll
    for (int nt = 0; nt < 4; nt++) {
        int col = n0 + wc * 64 + nt * 16 + l16;
        float bv = bsel[col & 1023];
#pragma unroll
        for (int mt = 0; mt < 4; mt++) {
            int row = m0 + wr * 64 + mt * 16 + quad * 4;
#pragma unroll
            for (int r = 0; r < 4; r++)
                store_out(&C[(size_t)(row + r) * ldc + col], acc[mt][nt][r] + bv);
        }
    }
}

// ---------------------------------------------------------------------------
// Flash attention over QKV[4096][3072] bf16. In-place output into Q region.
// Pair-packed V^T staging (ds_write_b32, 2-way banks), register prefetch of
// next K/V tile, 2 barriers/iter, exp2-domain online softmax.
// ---------------------------------------------------------------------------
#define SEQ 2048
#define BQ 64
#define BKV 64
#define LDK 72

__global__ __launch_bounds__(256) void attn(u16* __restrict__ QKV) {
    __shared__ __align__(16) u16 Ks[BKV * LDK];        // [kk][d]
    __shared__ __align__(16) u16 Vs[64 * LDK];         // [d][kk] (transposed)
    __shared__ __align__(16) u16 Ps[4 * 16 * LDK];     // per wave: [q][kk]

    const int tid = threadIdx.x;
    const int wave = tid >> 6, lane = tid & 63;
    const int quad = lane >> 4, l16 = lane & 15;
    const int h = blockIdx.y, bb = blockIdx.z;
    const int q0 = blockIdx.x * BQ;
    const size_t tok0 = (size_t)bb * SEQ;

    const u16* Qb = QKV + tok0 * 3072 + h * 64;
    const u16* Kb = QKV + tok0 * 3072 + 1024 + h * 64;
    const u16* Vb = QKV + tok0 * 3072 + 2048 + h * 64;

    const int qrow = q0 + wave * 16 + l16;
    short8 aq[2];
    aq[0] = *(const short8*)(Qb + (size_t)qrow * 3072 + quad * 8);
    aq[1] = *(const short8*)(Qb + (size_t)qrow * 3072 + 32 + quad * 8);

    float m_i[4], l_i[4];
#pragma unroll
    for (int r = 0; r < 4; r++) { m_i[r] = -1e30f; l_i[r] = 0.0f; }
    f32x4 o[4] = {};

    // K staging: 64 rows x 2 col-halves, vectorized
    const int srow = tid >> 2;           // 0..63
    const int scc = (tid & 3) * 16;      // 0/16/32/48
    // V staging: kk-pair x 8-d groups, pair-packed transposed writes
    const int pr = tid & 31;             // kk pair: rows 2pr, 2pr+1
    const int dg = tid >> 5;             // 0..7 -> d0 = dg*8
    u16* Ps_w = Ps + wave * 16 * LDK;

    const u16* kg = Kb + (size_t)srow * 3072 + scc;
    const u16* vg = Vb + (size_t)(2 * pr) * 3072 + dg * 8;

    uint4 k0r = *(const uint4*)(kg);
    uint4 k1r = *(const uint4*)(kg + 8);
    uint4 v0r = *(const uint4*)(vg);
    uint4 v1r = *(const uint4*)(vg + 3072);

    const float cs = 0.18033688011112042f;  // 0.125 * log2(e)

    for (int j0 = 0; j0 < SEQ; j0 += BKV) {
        // ---- write staged tile to LDS ----
        *(uint4*)(Ks + srow * LDK + scc) = k0r;
        *(uint4*)(Ks + srow * LDK + scc + 8) = k1r;
        {
            union { uint4 v; u16 u[8]; } a0, a1;
            a0.v = v0r; a1.v = v1r;
#pragma unroll
            for (int j = 0; j < 8; j++) {
                uint32_t w = (uint32_t)a0.u[j] | ((uint32_t)a1.u[j] << 16);
                *(uint32_t*)(Vs + (dg * 8 + j) * LDK + 2 * pr) = w;
            }
        }
        __syncthreads();

        // ---- prefetch next tile into registers (overlaps with compute) ----
        if (j0 + BKV < SEQ) {
            size_t off = (size_t)(j0 + BKV) * 3072;
            k0r = *(const uint4*)(kg + off);
            k1r = *(const uint4*)(kg + off + 8);
            v0r = *(const uint4*)(vg + off);
            v1r = *(const uint4*)(vg + off + 3072);
        }

        // ---- S = (Q K^T) * cs  (exp2 domain) ----
        f32x4 sacc[4];
#pragma unroll
        for (int kkt = 0; kkt < 4; kkt++) {
            f32x4 s = {};
#pragma unroll
            for (int k2 = 0; k2 < 2; k2++) {
                short8 bk = *(const short8*)(Ks + (kkt * 16 + l16) * LDK + k2 * 32 + quad * 8);
                s = __builtin_amdgcn_mfma_f32_16x16x32_bf16(aq[k2], bk, s, 0, 0, 0);
            }
            sacc[kkt] = s;
        }
#pragma unroll
        for (int kkt = 0; kkt < 4; kkt++)
#pragma unroll
            for (int r = 0; r < 4; r++) sacc[kkt][r] *= cs;

        // ---- online softmax (base-2) ----
        float rowmax[4];
#pragma unroll
        for (int r = 0; r < 4; r++) {
            float m = sacc[0][r];
            m = fmaxf(m, sacc[1][r]); m = fmaxf(m, sacc[2][r]); m = fmaxf(m, sacc[3][r]);
            rowmax[r] = m;
        }
#pragma unroll
        for (int off = 1; off < 16; off <<= 1)
#pragma unroll
            for (int r = 0; r < 4; r++)
                rowmax[r] = fmaxf(rowmax[r], __shfl_xor(rowmax[r], off, 64));

        float alpha[4];
#pragma unroll
        for (int r = 0; r < 4; r++) {
            float mn = fmaxf(m_i[r], rowmax[r]);
            alpha[r] = __builtin_amdgcn_exp2f(m_i[r] - mn);
            m_i[r] = mn;
        }
#pragma unroll
        for (int kkt = 0; kkt < 4; kkt++)
#pragma unroll
            for (int r = 0; r < 4; r++)
                sacc[kkt][r] = __builtin_amdgcn_exp2f(sacc[kkt][r] - m_i[r]);

        float lsum[4];
#pragma unroll
        for (int r = 0; r < 4; r++)
            lsum[r] = sacc[0][r] + sacc[1][r] + sacc[2][r] + sacc[3][r];
#pragma unroll
        for (int off = 1; off < 16; off <<= 1)
#pragma unroll
            for (int r = 0; r < 4; r++)
                lsum[r] += __shfl_xor(lsum[r], off, 64);
#pragma unroll
        for (int r = 0; r < 4; r++)
            l_i[r] = l_i[r] * alpha[r] + lsum[r];

#pragma unroll
        for (int dt = 0; dt < 4; dt++)
#pragma unroll
            for (int r = 0; r < 4; r++) o[dt][r] *= alpha[r];

        // ---- P -> LDS (wave-private; no block barrier needed) ----
#pragma unroll
        for (int kkt = 0; kkt < 4; kkt++)
#pragma unroll
            for (int r = 0; r < 4; r++)
                Ps_w[(quad * 4 + r) * LDK + kkt * 16 + l16] = f2bf(sacc[kkt][r]);

        // ---- O += P V ----
        short8 ap[2];
        ap[0] = *(const short8*)(Ps_w + l16 * LDK + quad * 8);
        ap[1] = *(const short8*)(Ps_w + l16 * LDK + 32 + quad * 8);
#pragma unroll
        for (int dt = 0; dt < 4; dt++) {
            f32x4 c = o[dt];
#pragma unroll
            for (int k2 = 0; k2 < 2; k2++) {
                short8 bv = *(const short8*)(Vs + (dt * 16 + l16) * LDK + k2 * 32 + quad * 8);
                c = __builtin_amdgcn_mfma_f32_16x16x32_bf16(ap[k2], bv, c, 0, 0, 0);
            }
            o[dt] = c;
        }
        __syncthreads();   // protect Ks/Vs for next iteration
    }

    float inv_l[4];
#pragma unroll
    for (int r = 0; r < 4; r++) inv_l[r] = 1.0f / l_i[r];
#pragma unroll
    for (int dt = 0; dt < 4; dt++)
#pragma unroll
        for (int r = 0; r < 4; r++) {
            size_t row = tok0 + q0 + wave * 16 + quad * 4 + r;
            QKV[row * 3072 + h * 64 + dt * 16 + l16] = f2bf(o[dt][r] * inv_l[r]);
        }
}

// ---------------------------------------------------------------------------
extern "C" void kernel_launch(void* const* d_in, const int* in_sizes, int n_in,
                              void* d_out, int out_size, void* d_ws, size_t ws_size,
                              hipStream_t stream) {
    const float* x  = (const float*)d_in[0];
    const float* wq = (const float*)d_in[1];
    const float* bq = (const float*)d_in[2];
    const float* wk = (const float*)d_in[3];
    const float* bk = (const float*)d_in[4];
    const float* wv = (const float*)d_in[5];
    const float* bv = (const float*)d_in[6];
    const float* wo = (const float*)d_in[7];
    const float* bo = (const float*)d_in[8];
    (void)in_sizes; (void)n_in; (void)out_size; (void)ws_size;

    u16* QKV = (u16*)d_ws;                              // [4096][3072] bf16, 24 MB
    u16* wT  = QKV + (size_t)4096 * 3072;               // [3][1024][1024] bf16, 6 MB
    u16* xb  = wT + (size_t)3 * 1024 * 1024;            // [4096][1024] bf16, 8 MB
    u16* woT = xb;                                      // reuses xb after gemm1 (stream-ordered)

    cvt_x<<<dim3(2048), dim3(256), 0, stream>>>(x, xb);
    transpose3<<<dim3(32, 32, 3), dim3(32, 8), 0, stream>>>(wq, wk, wv, wT);
    gemm_bt<u16><<<dim3(24, 32), 256, 0, stream>>>(xb, 1024, wT, 1024, bq, bk, bv,
                                                   QKV, 3072, 1024);
    // wo -> woT (overwrites xb; safe: gemm1 has consumed xb, stream-serialized)
    transpose3<<<dim3(32, 32, 1), dim3(32, 8), 0, stream>>>(wo, wo, wo, woT);
    attn<<<dim3(32, 16, 2), 256, 0, stream>>>(QKV);
    gemm_bt<float><<<dim3(8, 32), 256, 0, stream>>>(QKV, 3072, woT, 1024, bo, bo, bo,
                                                    (float*)d_out, 1024, 1024);
}

// Round 5
// 259.459 us; speedup vs baseline: 1.2185x; 1.0537x over previous
//
#include <hip/hip_runtime.h>
#include <hip/hip_bf16.h>
#include <stdint.h>

typedef unsigned short u16;
typedef __attribute__((ext_vector_type(8))) short short8;
typedef __attribute__((ext_vector_type(4))) float f32x4;

__device__ __forceinline__ u16 f2bf(float f) {
    union { float f; uint32_t u; } v; v.f = f;
    uint32_t r = (v.u + 0x7fffu + ((v.u >> 16) & 1u)) >> 16;
    return (u16)r;
}
// packed hw convert: two f32 -> two bf16 in one u32 (v_cvt_pk_bf16_f32 on gfx950)
__device__ __forceinline__ uint32_t pkbf(float a, float b) {
    union { __hip_bfloat162 h; uint32_t w; } u;
    u.h = __float22bfloat162_rn(float2{a, b});
    return u.w;
}
__device__ __forceinline__ void store_out(u16* p, float v) { *p = f2bf(v); }
__device__ __forceinline__ void store_out(float* p, float v) { *p = v; }

// ---------------------------------------------------------------------------
// x fp32 [4096*1024] -> bf16
// ---------------------------------------------------------------------------
__global__ void cvt_x(const float* __restrict__ x, u16* __restrict__ xb) {
    int i = (blockIdx.x * 256 + threadIdx.x) * 8;
    float4 a = *(const float4*)(x + i);
    float4 b = *(const float4*)(x + i + 4);
    union { uint32_t w[4]; uint4 v; } o;
    o.w[0] = pkbf(a.x, a.y); o.w[1] = pkbf(a.z, a.w);
    o.w[2] = pkbf(b.x, b.y); o.w[3] = pkbf(b.z, b.w);
    *(uint4*)(xb + i) = o.v;
}

// ---------------------------------------------------------------------------
// fp32 [1024][1024] -> bf16 transposed; z selects among 3 sources
// ---------------------------------------------------------------------------
__global__ void transpose3(const float* __restrict__ w0, const float* __restrict__ w1,
                           const float* __restrict__ w2, u16* __restrict__ out) {
    const int z = blockIdx.z;
    const float* in = (z == 0) ? w0 : (z == 1) ? w1 : w2;
    u16* o = out + (size_t)z * 1024 * 1024;
    __shared__ u16 tile[32][33];
    int x = blockIdx.x * 32 + threadIdx.x;
    int y0 = blockIdx.y * 32;
#pragma unroll
    for (int j = threadIdx.y; j < 32; j += 8)
        tile[j][threadIdx.x] = f2bf(in[(size_t)(y0 + j) * 1024 + x]);
    __syncthreads();
    int ox = blockIdx.y * 32 + threadIdx.x;
    int oy0 = blockIdx.x * 32;
#pragma unroll
    for (int j = threadIdx.y; j < 32; j += 8)
        o[(size_t)(oy0 + j) * 1024 + ox] = tile[threadIdx.x][j];
}

// ---------------------------------------------------------------------------
// GEMM (B^T bf16): C[M,N] = A_bf16[M,K] @ BT[N,K]^T + bias_f32. OutT=u16/float.
// ---------------------------------------------------------------------------
#define GBM 128
#define GBN 128
#define GBK 32
#define LDA 40

template <typename OutT>
__global__ __launch_bounds__(256) void gemm_bt(
    const u16* __restrict__ A, int lda,
    const u16* __restrict__ BT, int ldb,
    const float* __restrict__ bias0, const float* __restrict__ bias1,
    const float* __restrict__ bias2,
    OutT* __restrict__ C, int ldc, int K) {
    __shared__ __align__(16) u16 As[GBM * LDA];
    __shared__ __align__(16) u16 Bs[GBN * LDA];

    const int tid = threadIdx.x;
    const int wave = tid >> 6, lane = tid & 63;
    const int quad = lane >> 4, l16 = lane & 15;
    const int wr = wave >> 1, wc = wave & 1;
    const int m0 = blockIdx.y * GBM, n0 = blockIdx.x * GBN;

    const int seg = n0 >> 10;
    const float* bsel = (seg == 0) ? bias0 : (seg == 1) ? bias1 : bias2;

    f32x4 acc[4][4] = {};

    const int sr = tid >> 1;
    const int sc = (tid & 1) * 16;
    const u16* Ag = A + (size_t)(m0 + sr) * lda + sc;
    const u16* Bg = BT + (size_t)(n0 + sr) * ldb + sc;
    uint4* AsW = (uint4*)(As + sr * LDA + sc);
    uint4* BsW = (uint4*)(Bs + sr * LDA + sc);

    for (int kb = 0; kb < K; kb += GBK) {
        uint4 av0 = *(const uint4*)(Ag + kb);
        uint4 av1 = *(const uint4*)(Ag + kb + 8);
        uint4 bv0 = *(const uint4*)(Bg + kb);
        uint4 bv1 = *(const uint4*)(Bg + kb + 8);
        AsW[0] = av0; AsW[1] = av1;
        BsW[0] = bv0; BsW[1] = bv1;
        __syncthreads();

        short8 af[4], bf[4];
#pragma unroll
        for (int mt = 0; mt < 4; mt++)
            af[mt] = *(const short8*)(As + (wr * 64 + mt * 16 + l16) * LDA + quad * 8);
#pragma unroll
        for (int nt = 0; nt < 4; nt++)
            bf[nt] = *(const short8*)(Bs + (wc * 64 + nt * 16 + l16) * LDA + quad * 8);
#pragma unroll
        for (int mt = 0; mt < 4; mt++)
#pragma unroll
            for (int nt = 0; nt < 4; nt++)
                acc[mt][nt] = __builtin_amdgcn_mfma_f32_16x16x32_bf16(
                    af[mt], bf[nt], acc[mt][nt], 0, 0, 0);
        __syncthreads();
    }

#pragma unroll
    for (int nt = 0; nt < 4; nt++) {
        int col = n0 + wc * 64 + nt * 16 + l16;
        float bv = bsel[col & 1023];
#pragma unroll
        for (int mt = 0; mt < 4; mt++) {
            int row = m0 + wr * 64 + mt * 16 + quad * 4;
#pragma unroll
            for (int r = 0; r < 4; r++)
                store_out(&C[(size_t)(row + r) * ldc + col], acc[mt][nt][r] + bv);
        }
    }
}

// ---------------------------------------------------------------------------
// Flash attention, BKV=128, Ps aliased into Ks (3 barriers / 128 kv).
// QKV[4096][3072] bf16; in-place output into Q region.
// ---------------------------------------------------------------------------
#define SEQ 2048
#define BQ 64
#define BKV 128
#define LDK 72     // Ks row: 64 d + 8 pad
#define LDKV 136   // Vs/Ps row: 128 kk + 8 pad

__global__ __launch_bounds__(256) void attn(u16* __restrict__ QKV) {
    __shared__ __align__(16) u16 Ks[BKV * LDK];        // [kk][d]; re-used as Ps after B2
    __shared__ __align__(16) u16 Vs[64 * LDKV];        // [d][kk] (transposed)

    const int tid = threadIdx.x;
    const int wave = tid >> 6, lane = tid & 63;
    const int quad = lane >> 4, l16 = lane & 15;
    const int h = blockIdx.y, bb = blockIdx.z;
    const int q0 = blockIdx.x * BQ;
    const size_t tok0 = (size_t)bb * SEQ;

    const u16* Qb = QKV + tok0 * 3072 + h * 64;
    const u16* Kb = QKV + tok0 * 3072 + 1024 + h * 64;
    const u16* Vb = QKV + tok0 * 3072 + 2048 + h * 64;

    const int qrow = q0 + wave * 16 + l16;
    short8 aq[2];
    aq[0] = *(const short8*)(Qb + (size_t)qrow * 3072 + quad * 8);
    aq[1] = *(const short8*)(Qb + (size_t)qrow * 3072 + 32 + quad * 8);

    float m_i[4], l_i[4];
#pragma unroll
    for (int r = 0; r < 4; r++) { m_i[r] = -1e30f; l_i[r] = 0.0f; }
    f32x4 o[4] = {};

    // K staging: rows srow, srow+64; 16-col segment scc
    const int srow = tid >> 2;           // 0..63
    const int scc = (tid & 3) * 16;      // 0/16/32/48
    // V staging: kv-pair rows 2pr,2pr+1; d segment dg*16 (dg = wave)
    const int pr = tid & 63;
    const int dg = wave;
    // Ps region aliased into Ks: per wave 16 q-rows x LDKV
    u16* Ps_w = Ks + wave * 16 * LDKV;   // 4*16*136 = 8704 <= 128*72 = 9216

    const u16* kg = Kb + (size_t)srow * 3072 + scc;
    const u16* vg = Vb + (size_t)(2 * pr) * 3072 + dg * 16;

    uint4 k0r = *(const uint4*)(kg);
    uint4 k1r = *(const uint4*)(kg + 8);
    uint4 k2r = *(const uint4*)(kg + (size_t)64 * 3072);
    uint4 k3r = *(const uint4*)(kg + (size_t)64 * 3072 + 8);
    uint4 va0 = *(const uint4*)(vg);
    uint4 va1 = *(const uint4*)(vg + 8);
    uint4 vb0 = *(const uint4*)(vg + 3072);
    uint4 vb1 = *(const uint4*)(vg + 3072 + 8);

    const float cs = 0.18033688011112042f;  // (1/8) * log2(e)

    for (int j0 = 0; j0 < SEQ; j0 += BKV) {
        // ---- stage K rows + pair-packed V^T ----
        *(uint4*)(Ks + srow * LDK + scc) = k0r;
        *(uint4*)(Ks + srow * LDK + scc + 8) = k1r;
        *(uint4*)(Ks + (srow + 64) * LDK + scc) = k2r;
        *(uint4*)(Ks + (srow + 64) * LDK + scc + 8) = k3r;
        {
            union { uint4 v[2]; u16 u[16]; } a, b;
            a.v[0] = va0; a.v[1] = va1; b.v[0] = vb0; b.v[1] = vb1;
#pragma unroll
            for (int j = 0; j < 16; j++) {
                uint32_t w = (uint32_t)a.u[j] | ((uint32_t)b.u[j] << 16);
                *(uint32_t*)(Vs + (dg * 16 + j) * LDKV + 2 * pr) = w;
            }
        }
        __syncthreads();   // B1: staged tile visible

        // ---- prefetch next tile ----
        if (j0 + BKV < SEQ) {
            size_t off = (size_t)(j0 + BKV) * 3072;
            k0r = *(const uint4*)(kg + off);
            k1r = *(const uint4*)(kg + off + 8);
            k2r = *(const uint4*)(kg + off + (size_t)64 * 3072);
            k3r = *(const uint4*)(kg + off + (size_t)64 * 3072 + 8);
            va0 = *(const uint4*)(vg + off);
            va1 = *(const uint4*)(vg + off + 8);
            vb0 = *(const uint4*)(vg + off + 3072);
            vb1 = *(const uint4*)(vg + off + 3072 + 8);
        }

        // ---- S = Q K^T (raw logits; scale folded into exp2) ----
        f32x4 sacc[8];
#pragma unroll
        for (int kkt = 0; kkt < 8; kkt++) {
            f32x4 s = {};
#pragma unroll
            for (int k2 = 0; k2 < 2; k2++) {
                short8 bk = *(const short8*)(Ks + (kkt * 16 + l16) * LDK + k2 * 32 + quad * 8);
                s = __builtin_amdgcn_mfma_f32_16x16x32_bf16(aq[k2], bk, s, 0, 0, 0);
            }
            sacc[kkt] = s;
        }

        // ---- online softmax (raw-domain max, exp2 with fma-folded scale) ----
        float rowmax[4];
#pragma unroll
        for (int r = 0; r < 4; r++) {
            float m = sacc[0][r];
#pragma unroll
            for (int kkt = 1; kkt < 8; kkt++) m = fmaxf(m, sacc[kkt][r]);
            rowmax[r] = m;
        }
#pragma unroll
        for (int off = 1; off < 16; off <<= 1)
#pragma unroll
            for (int r = 0; r < 4; r++)
                rowmax[r] = fmaxf(rowmax[r], __shfl_xor(rowmax[r], off, 64));

        float alpha[4], nmcs[4];
#pragma unroll
        for (int r = 0; r < 4; r++) {
            float mn = fmaxf(m_i[r], rowmax[r]);
            alpha[r] = __builtin_amdgcn_exp2f((m_i[r] - mn) * cs);
            m_i[r] = mn;
            nmcs[r] = -mn * cs;
        }
#pragma unroll
        for (int kkt = 0; kkt < 8; kkt++)
#pragma unroll
            for (int r = 0; r < 4; r++)
                sacc[kkt][r] = __builtin_amdgcn_exp2f(fmaf(sacc[kkt][r], cs, nmcs[r]));

        float lsum[4];
#pragma unroll
        for (int r = 0; r < 4; r++) {
            float s = sacc[0][r];
#pragma unroll
            for (int kkt = 1; kkt < 8; kkt++) s += sacc[kkt][r];
            lsum[r] = s;
        }
#pragma unroll
        for (int off = 1; off < 16; off <<= 1)
#pragma unroll
            for (int r = 0; r < 4; r++)
                lsum[r] += __shfl_xor(lsum[r], off, 64);
#pragma unroll
        for (int r = 0; r < 4; r++)
            l_i[r] = l_i[r] * alpha[r] + lsum[r];

#pragma unroll
        for (int dt = 0; dt < 4; dt++)
#pragma unroll
            for (int r = 0; r < 4; r++) o[dt][r] *= alpha[r];

        __syncthreads();   // B2: all waves done reading Ks -> safe to alias as Ps

        // ---- P -> Ps (hw packed bf16 convert; wave-private region) ----
#pragma unroll
        for (int kkt = 0; kkt < 8; kkt++) {
#pragma unroll
            for (int rp = 0; rp < 4; rp += 2) {
                uint32_t w = pkbf(sacc[kkt][rp], sacc[kkt][rp + 1]);
                Ps_w[(quad * 4 + rp) * LDKV + kkt * 16 + l16] = (u16)w;
                Ps_w[(quad * 4 + rp + 1) * LDKV + kkt * 16 + l16] = (u16)(w >> 16);
            }
        }

        // ---- O += P V ----
        short8 ap[4];
#pragma unroll
        for (int k2 = 0; k2 < 4; k2++)
            ap[k2] = *(const short8*)(Ps_w + l16 * LDKV + k2 * 32 + quad * 8);
#pragma unroll
        for (int dt = 0; dt < 4; dt++) {
            f32x4 c = o[dt];
#pragma unroll
            for (int k2 = 0; k2 < 4; k2++) {
                short8 bv = *(const short8*)(Vs + (dt * 16 + l16) * LDKV + k2 * 32 + quad * 8);
                c = __builtin_amdgcn_mfma_f32_16x16x32_bf16(ap[k2], bv, c, 0, 0, 0);
            }
            o[dt] = c;
        }
        __syncthreads();   // B3: Ps/Vs reads done before next staging
    }

    float inv_l[4];
#pragma unroll
    for (int r = 0; r < 4; r++) inv_l[r] = 1.0f / l_i[r];
#pragma unroll
    for (int dt = 0; dt < 4; dt++)
#pragma unroll
        for (int r = 0; r < 4; r++) {
            size_t row = tok0 + q0 + wave * 16 + quad * 4 + r;
            QKV[row * 3072 + h * 64 + dt * 16 + l16] = f2bf(o[dt][r] * inv_l[r]);
        }
}

// ---------------------------------------------------------------------------
extern "C" void kernel_launch(void* const* d_in, const int* in_sizes, int n_in,
                              void* d_out, int out_size, void* d_ws, size_t ws_size,
                              hipStream_t stream) {
    const float* x  = (const float*)d_in[0];
    const float* wq = (const float*)d_in[1];
    const float* bq = (const float*)d_in[2];
    const float* wk = (const float*)d_in[3];
    const float* bk = (const float*)d_in[4];
    const float* wv = (const float*)d_in[5];
    const float* bv = (const float*)d_in[6];
    const float* wo = (const float*)d_in[7];
    const float* bo = (const float*)d_in[8];
    (void)in_sizes; (void)n_in; (void)out_size; (void)ws_size;

    u16* QKV = (u16*)d_ws;                              // [4096][3072] bf16, 24 MB
    u16* wT  = QKV + (size_t)4096 * 3072;               // [3][1024][1024] bf16, 6 MB
    u16* xb  = wT + (size_t)3 * 1024 * 1024;            // [4096][1024] bf16, 8 MB
    u16* woT = xb;                                      // reuses xb after gemm1

    cvt_x<<<dim3(2048), dim3(256), 0, stream>>>(x, xb);
    transpose3<<<dim3(32, 32, 3), dim3(32, 8), 0, stream>>>(wq, wk, wv, wT);
    gemm_bt<u16><<<dim3(24, 32), 256, 0, stream>>>(xb, 1024, wT, 1024, bq, bk, bv,
                                                   QKV, 3072, 1024);
    transpose3<<<dim3(32, 32, 1), dim3(32, 8), 0, stream>>>(wo, wo, wo, woT);
    attn<<<dim3(32, 16, 2), 256, 0, stream>>>(QKV);
    gemm_bt<float><<<dim3(8, 32), 256, 0, stream>>>(QKV, 3072, woT, 1024, bo, bo, bo,
                                                    (float*)d_out, 1024, 1024);
}

// Round 6
// 254.848 us; speedup vs baseline: 1.2405x; 1.0181x over previous
//
#include <hip/hip_runtime.h>
#include <hip/hip_bf16.h>
#include <stdint.h>

typedef unsigned short u16;
typedef __attribute__((ext_vector_type(8))) short short8;
typedef __attribute__((ext_vector_type(4))) float f32x4;

__device__ __forceinline__ u16 f2bf(float f) {
    union { float f; uint32_t u; } v; v.f = f;
    uint32_t r = (v.u + 0x7fffu + ((v.u >> 16) & 1u)) >> 16;
    return (u16)r;
}
__device__ __forceinline__ uint32_t pkbf(float a, float b) {
    union { __hip_bfloat162 h; uint32_t w; } u;
    u.h = __float22bfloat162_rn(float2{a, b});
    return u.w;
}
__device__ __forceinline__ void store_out(u16* p, float v) { *p = f2bf(v); }
__device__ __forceinline__ void store_out(float* p, float v) { *p = v; }

// async global->LDS, 16B per lane; LDS dest = wave-uniform base + lane*16
__device__ __forceinline__ void async_ld16(const u16* g, u16* l) {
    __builtin_amdgcn_global_load_lds(
        (const __attribute__((address_space(1))) void*)g,
        (__attribute__((address_space(3))) void*)l, 16, 0, 0);
}

// ---------------------------------------------------------------------------
// x fp32 [4096*1024] -> bf16
// ---------------------------------------------------------------------------
__global__ void cvt_x(const float* __restrict__ x, u16* __restrict__ xb) {
    int i = (blockIdx.x * 256 + threadIdx.x) * 8;
    float4 a = *(const float4*)(x + i);
    float4 b = *(const float4*)(x + i + 4);
    union { uint32_t w[4]; uint4 v; } o;
    o.w[0] = pkbf(a.x, a.y); o.w[1] = pkbf(a.z, a.w);
    o.w[2] = pkbf(b.x, b.y); o.w[3] = pkbf(b.z, b.w);
    *(uint4*)(xb + i) = o.v;
}

// ---------------------------------------------------------------------------
// fp32 [1024][1024] -> bf16 transposed; z selects among 3 sources
// ---------------------------------------------------------------------------
__global__ void transpose3(const float* __restrict__ w0, const float* __restrict__ w1,
                           const float* __restrict__ w2, u16* __restrict__ out) {
    const int z = blockIdx.z;
    const float* in = (z == 0) ? w0 : (z == 1) ? w1 : w2;
    u16* o = out + (size_t)z * 1024 * 1024;
    __shared__ u16 tile[32][33];
    int x = blockIdx.x * 32 + threadIdx.x;
    int y0 = blockIdx.y * 32;
#pragma unroll
    for (int j = threadIdx.y; j < 32; j += 8)
        tile[j][threadIdx.x] = f2bf(in[(size_t)(y0 + j) * 1024 + x]);
    __syncthreads();
    int ox = blockIdx.y * 32 + threadIdx.x;
    int oy0 = blockIdx.x * 32;
#pragma unroll
    for (int j = threadIdx.y; j < 32; j += 8)
        o[(size_t)(oy0 + j) * 1024 + ox] = tile[threadIdx.x][j];
}

// ---------------------------------------------------------------------------
// GEMM (B^T bf16, async-LDS staging): C[M,N] = A[M,K] @ BT[N,K]^T + bias_f32.
// 128x128 tile, BK=32, tiles row-major [128][32] NO PAD (global_load_lds
// requires lane-contiguous layout; frag-read bank pattern is minimal anyway).
// ---------------------------------------------------------------------------
#define GBM 128
#define GBN 128
#define GBK 32

template <typename OutT>
__global__ __launch_bounds__(256) void gemm_bt(
    const u16* __restrict__ A, int lda,
    const u16* __restrict__ BT, int ldb,
    const float* __restrict__ bias0, const float* __restrict__ bias1,
    const float* __restrict__ bias2,
    OutT* __restrict__ C, int ldc, int K) {
    __shared__ __align__(16) u16 As[GBM * GBK];
    __shared__ __align__(16) u16 Bs[GBN * GBK];

    const int tid = threadIdx.x;
    const int wave = tid >> 6, lane = tid & 63;
    const int quad = lane >> 4, l16 = lane & 15;
    const int wr = wave >> 1, wc = wave & 1;
    const int m0 = blockIdx.y * GBM, n0 = blockIdx.x * GBN;

    const int seg = n0 >> 10;
    const float* bsel = (seg == 0) ? bias0 : (seg == 1) ? bias1 : bias2;

    f32x4 acc[4][4] = {};

    // staging: lane l of wave w covers flat elem (w*64+l)*8
    //   = row (w*16 + l>>2), col (l&3)*8 of the [128][32] tile (two halves).
    const int srow = tid >> 2;            // 0..63
    const int scol = (tid & 3) * 8;       // 0/8/16/24
    const u16* Ag0 = A + (size_t)(m0 + srow) * lda + scol;
    const u16* Ag1 = Ag0 + (size_t)64 * lda;
    const u16* Bg0 = BT + (size_t)(n0 + srow) * ldb + scol;
    const u16* Bg1 = Bg0 + (size_t)64 * ldb;
    u16* As0 = As + (wave << 9);          // wave-uniform LDS bases
    u16* As1 = As0 + 64 * GBK;
    u16* Bs0 = Bs + (wave << 9);
    u16* Bs1 = Bs0 + 64 * GBK;

    for (int kb = 0; kb < K; kb += GBK) {
        async_ld16(Ag0 + kb, As0);
        async_ld16(Ag1 + kb, As1);
        async_ld16(Bg0 + kb, Bs0);
        async_ld16(Bg1 + kb, Bs1);
        __syncthreads();

        short8 af[4], bf[4];
#pragma unroll
        for (int mt = 0; mt < 4; mt++)
            af[mt] = *(const short8*)(As + (wr * 64 + mt * 16 + l16) * GBK + quad * 8);
#pragma unroll
        for (int nt = 0; nt < 4; nt++)
            bf[nt] = *(const short8*)(Bs + (wc * 64 + nt * 16 + l16) * GBK + quad * 8);
#pragma unroll
        for (int mt = 0; mt < 4; mt++)
#pragma unroll
            for (int nt = 0; nt < 4; nt++)
                acc[mt][nt] = __builtin_amdgcn_mfma_f32_16x16x32_bf16(
                    af[mt], bf[nt], acc[mt][nt], 0, 0, 0);
        __syncthreads();
    }

#pragma unroll
    for (int nt = 0; nt < 4; nt++) {
        int col = n0 + wc * 64 + nt * 16 + l16;
        float bv = bsel[col & 1023];
#pragma unroll
        for (int mt = 0; mt < 4; mt++) {
            int row = m0 + wr * 64 + mt * 16 + quad * 4;
#pragma unroll
            for (int r = 0; r < 4; r++)
                store_out(&C[(size_t)(row + r) * ldc + col], acc[mt][nt][r] + bv);
        }
    }
}

// ---------------------------------------------------------------------------
// Flash attention, BKV=128, Ps aliased into Ks (3 barriers / 128 kv).
// QKV[4096][3072] bf16; in-place output into Q region.
// ---------------------------------------------------------------------------
#define SEQ 2048
#define BQ 64
#define BKV 128
#define LDK 72     // Ks row: 64 d + 8 pad
#define LDKV 136   // Vs/Ps row: 128 kk + 8 pad

__global__ __launch_bounds__(256) void attn(u16* __restrict__ QKV) {
    __shared__ __align__(16) u16 Ks[BKV * LDK];        // [kk][d]; re-used as Ps after B2
    __shared__ __align__(16) u16 Vs[64 * LDKV];        // [d][kk] (transposed)

    const int tid = threadIdx.x;
    const int wave = tid >> 6, lane = tid & 63;
    const int quad = lane >> 4, l16 = lane & 15;
    const int h = blockIdx.y, bb = blockIdx.z;
    const int q0 = blockIdx.x * BQ;
    const size_t tok0 = (size_t)bb * SEQ;

    const u16* Qb = QKV + tok0 * 3072 + h * 64;
    const u16* Kb = QKV + tok0 * 3072 + 1024 + h * 64;
    const u16* Vb = QKV + tok0 * 3072 + 2048 + h * 64;

    const int qrow = q0 + wave * 16 + l16;
    short8 aq[2];
    aq[0] = *(const short8*)(Qb + (size_t)qrow * 3072 + quad * 8);
    aq[1] = *(const short8*)(Qb + (size_t)qrow * 3072 + 32 + quad * 8);

    float m_i[4], l_i[4];
#pragma unroll
    for (int r = 0; r < 4; r++) { m_i[r] = -1e30f; l_i[r] = 0.0f; }
    f32x4 o[4] = {};

    const int srow = tid >> 2;           // 0..63
    const int scc = (tid & 3) * 16;      // 0/16/32/48
    const int pr = tid & 63;
    const int dg = wave;
    u16* Ps_w = Ks + wave * 16 * LDKV;   // 4*16*136 = 8704 <= 128*72 = 9216

    const u16* kg = Kb + (size_t)srow * 3072 + scc;
    const u16* vg = Vb + (size_t)(2 * pr) * 3072 + dg * 16;

    uint4 k0r = *(const uint4*)(kg);
    uint4 k1r = *(const uint4*)(kg + 8);
    uint4 k2r = *(const uint4*)(kg + (size_t)64 * 3072);
    uint4 k3r = *(const uint4*)(kg + (size_t)64 * 3072 + 8);
    uint4 va0 = *(const uint4*)(vg);
    uint4 va1 = *(const uint4*)(vg + 8);
    uint4 vb0 = *(const uint4*)(vg + 3072);
    uint4 vb1 = *(const uint4*)(vg + 3072 + 8);

    const float cs = 0.18033688011112042f;  // (1/8) * log2(e)

    for (int j0 = 0; j0 < SEQ; j0 += BKV) {
        *(uint4*)(Ks + srow * LDK + scc) = k0r;
        *(uint4*)(Ks + srow * LDK + scc + 8) = k1r;
        *(uint4*)(Ks + (srow + 64) * LDK + scc) = k2r;
        *(uint4*)(Ks + (srow + 64) * LDK + scc + 8) = k3r;
        {
            union { uint4 v[2]; u16 u[16]; } a, b;
            a.v[0] = va0; a.v[1] = va1; b.v[0] = vb0; b.v[1] = vb1;
#pragma unroll
            for (int j = 0; j < 16; j++) {
                uint32_t w = (uint32_t)a.u[j] | ((uint32_t)b.u[j] << 16);
                *(uint32_t*)(Vs + (dg * 16 + j) * LDKV + 2 * pr) = w;
            }
        }
        __syncthreads();   // B1

        if (j0 + BKV < SEQ) {
            size_t off = (size_t)(j0 + BKV) * 3072;
            k0r = *(const uint4*)(kg + off);
            k1r = *(const uint4*)(kg + off + 8);
            k2r = *(const uint4*)(kg + off + (size_t)64 * 3072);
            k3r = *(const uint4*)(kg + off + (size_t)64 * 3072 + 8);
            va0 = *(const uint4*)(vg + off);
            va1 = *(const uint4*)(vg + off + 8);
            vb0 = *(const uint4*)(vg + off + 3072);
            vb1 = *(const uint4*)(vg + off + 3072 + 8);
        }

        f32x4 sacc[8];
#pragma unroll
        for (int kkt = 0; kkt < 8; kkt++) {
            f32x4 s = {};
#pragma unroll
            for (int k2 = 0; k2 < 2; k2++) {
                short8 bk = *(const short8*)(Ks + (kkt * 16 + l16) * LDK + k2 * 32 + quad * 8);
                s = __builtin_amdgcn_mfma_f32_16x16x32_bf16(aq[k2], bk, s, 0, 0, 0);
            }
            sacc[kkt] = s;
        }

        float rowmax[4];
#pragma unroll
        for (int r = 0; r < 4; r++) {
            float m = sacc[0][r];
#pragma unroll
            for (int kkt = 1; kkt < 8; kkt++) m = fmaxf(m, sacc[kkt][r]);
            rowmax[r] = m;
        }
#pragma unroll
        for (int off = 1; off < 16; off <<= 1)
#pragma unroll
            for (int r = 0; r < 4; r++)
                rowmax[r] = fmaxf(rowmax[r], __shfl_xor(rowmax[r], off, 64));

        float alpha[4], nmcs[4];
#pragma unroll
        for (int r = 0; r < 4; r++) {
            float mn = fmaxf(m_i[r], rowmax[r]);
            alpha[r] = __builtin_amdgcn_exp2f((m_i[r] - mn) * cs);
            m_i[r] = mn;
            nmcs[r] = -mn * cs;
        }
#pragma unroll
        for (int kkt = 0; kkt < 8; kkt++)
#pragma unroll
            for (int r = 0; r < 4; r++)
                sacc[kkt][r] = __builtin_amdgcn_exp2f(fmaf(sacc[kkt][r], cs, nmcs[r]));

        float lsum[4];
#pragma unroll
        for (int r = 0; r < 4; r++) {
            float s = sacc[0][r];
#pragma unroll
            for (int kkt = 1; kkt < 8; kkt++) s += sacc[kkt][r];
            lsum[r] = s;
        }
#pragma unroll
        for (int off = 1; off < 16; off <<= 1)
#pragma unroll
            for (int r = 0; r < 4; r++)
                lsum[r] += __shfl_xor(lsum[r], off, 64);
#pragma unroll
        for (int r = 0; r < 4; r++)
            l_i[r] = l_i[r] * alpha[r] + lsum[r];

#pragma unroll
        for (int dt = 0; dt < 4; dt++)
#pragma unroll
            for (int r = 0; r < 4; r++) o[dt][r] *= alpha[r];

        __syncthreads();   // B2: Ks reads done -> alias as Ps

#pragma unroll
        for (int kkt = 0; kkt < 8; kkt++) {
#pragma unroll
            for (int rp = 0; rp < 4; rp += 2) {
                uint32_t w = pkbf(sacc[kkt][rp], sacc[kkt][rp + 1]);
                Ps_w[(quad * 4 + rp) * LDKV + kkt * 16 + l16] = (u16)w;
                Ps_w[(quad * 4 + rp + 1) * LDKV + kkt * 16 + l16] = (u16)(w >> 16);
            }
        }

        short8 ap[4];
#pragma unroll
        for (int k2 = 0; k2 < 4; k2++)
            ap[k2] = *(const short8*)(Ps_w + l16 * LDKV + k2 * 32 + quad * 8);
#pragma unroll
        for (int dt = 0; dt < 4; dt++) {
            f32x4 c = o[dt];
#pragma unroll
            for (int k2 = 0; k2 < 4; k2++) {
                short8 bv = *(const short8*)(Vs + (dt * 16 + l16) * LDKV + k2 * 32 + quad * 8);
                c = __builtin_amdgcn_mfma_f32_16x16x32_bf16(ap[k2], bv, c, 0, 0, 0);
            }
            o[dt] = c;
        }
        __syncthreads();   // B3
    }

    float inv_l[4];
#pragma unroll
    for (int r = 0; r < 4; r++) inv_l[r] = 1.0f / l_i[r];
#pragma unroll
    for (int dt = 0; dt < 4; dt++)
#pragma unroll
        for (int r = 0; r < 4; r++) {
            size_t row = tok0 + q0 + wave * 16 + quad * 4 + r;
            QKV[row * 3072 + h * 64 + dt * 16 + l16] = f2bf(o[dt][r] * inv_l[r]);
        }
}

// ---------------------------------------------------------------------------
extern "C" void kernel_launch(void* const* d_in, const int* in_sizes, int n_in,
                              void* d_out, int out_size, void* d_ws, size_t ws_size,
                              hipStream_t stream) {
    const float* x  = (const float*)d_in[0];
    const float* wq = (const float*)d_in[1];
    const float* bq = (const float*)d_in[2];
    const float* wk = (const float*)d_in[3];
    const float* bk = (const float*)d_in[4];
    const float* wv = (const float*)d_in[5];
    const float* bv = (const float*)d_in[6];
    const float* wo = (const float*)d_in[7];
    const float* bo = (const float*)d_in[8];
    (void)in_sizes; (void)n_in; (void)out_size; (void)ws_size;

    u16* QKV = (u16*)d_ws;                              // [4096][3072] bf16, 24 MB
    u16* wT  = QKV + (size_t)4096 * 3072;               // [3][1024][1024] bf16, 6 MB
    u16* xb  = wT + (size_t)3 * 1024 * 1024;            // [4096][1024] bf16, 8 MB
    u16* woT = xb;                                      // reuses xb after gemm1

    cvt_x<<<dim3(2048), dim3(256), 0, stream>>>(x, xb);
    transpose3<<<dim3(32, 32, 3), dim3(32, 8), 0, stream>>>(wq, wk, wv, wT);
    gemm_bt<u16><<<dim3(24, 32), 256, 0, stream>>>(xb, 1024, wT, 1024, bq, bk, bv,
                                                   QKV, 3072, 1024);
    transpose3<<<dim3(32, 32, 1), dim3(32, 8), 0, stream>>>(wo, wo, wo, woT);
    attn<<<dim3(32, 16, 2), 256, 0, stream>>>(QKV);
    gemm_bt<float><<<dim3(8, 32), 256, 0, stream>>>(QKV, 3072, woT, 1024, bo, bo, bo,
                                                    (float*)d_out, 1024, 1024);
}